// Round 1
// baseline (332.708 us; speedup 1.0000x reference)
//
#include <hip/hip_runtime.h>

// Problem: N=1024 images of (16,32,32); E=4096 signed edges; pooled pos/neg by
// sign; concat -> 48ch; 3x (3x3 conv pad1 + leaky 0.1): 48->32->32->16.
//
// Design (R1):
//  K1 pool_kernel: one block per node; scan edges -> LDS adjacency; gather-sum
//     neighbor feats (float4, L3-resident) -> pos/neg as fp16 in d_ws.
//  K2 conv_kernel: one block (512 thr, 8 waves) per image. Fully fused:
//     stage [feats|pos|neg] channel-last fp16 in LDS (34x34x56, halo zeroed),
//     conv1/2/3 as implicit GEMM with mfma_f32_16x16x32_f16
//     (A[m=lane&15][k=quad*8+j], B[k=quad*8+j][n=lane&15],
//      D row=(lane>>4)*4+r col=lane&15 -- doc-verified layouts).
//     y1/y2 round-trip through LDS only (34x34x40); weights LDS-resident with
//     K-stride padded (456/296) to spread A-read banks. No HBM intermediates.

#define NIMG 1024
#define CHW  16384      // 16*32*32
#define NEDGE 4096
#define MAXD 192

#define ICP1 56         // 48 channels padded; stride 112B: 16B-aligned, 8 bank-quads
#define KP1  456        // K1=432 padded (>=448 read range); stride 912B: 16B-aligned, not bank-uniform
#define ICP2 40         // 32 channels padded; stride 80B
#define KCV2 288        // K2 = 9*32 exact
#define KP2  296
#define XSZ (34*34*ICP1)   // 64736 halves = 129472 B
#define WSZ (32*KP1)       // 14592 halves =  29184 B   (total 158656 B <= 160 KiB)

typedef __attribute__((ext_vector_type(8))) _Float16 half8;
typedef __attribute__((ext_vector_type(4))) _Float16 half4;
typedef __attribute__((ext_vector_type(4))) float float4v;

__device__ __forceinline__ float leaky(float x) { return x > 0.f ? x : 0.1f * x; }

// ---------------------------------------------------------------- K1: pooling
__global__ __launch_bounds__(256) void pool_kernel(
    const float* __restrict__ feats, const int* __restrict__ edges,
    _Float16* __restrict__ pos, _Float16* __restrict__ neg)
{
    __shared__ int lst[MAXD];
    __shared__ int cnt;
    const int n = blockIdx.x;
    const int tid = threadIdx.x;
    if (tid == 0) cnt = 0;
    __syncthreads();
    // dtype hedge: int64 layout => word[1] = high word of src0 = 0;
    // int32 layout => word[1] = sign0 = +-1 (never 0).
    const bool is64 = (edges[1] == 0);
    for (int e = tid; e < NEDGE; e += 256) {
        int s, sg, d;
        if (is64) { s = edges[6*e]; sg = edges[6*e + 2]; d = edges[6*e + 4]; }
        else      { s = edges[3*e]; sg = edges[3*e + 1]; d = edges[3*e + 2]; }
        if (s == n) { int i = atomicAdd(&cnt, 1); if (i < MAXD) lst[i] = (d << 1) | (int)(sg > 0); }
        if (d == n) { int i = atomicAdd(&cnt, 1); if (i < MAXD) lst[i] = (s << 1) | (int)(sg > 0); }
    }
    __syncthreads();
    int m = cnt; if (m > MAXD) m = MAXD;
    const float4v* f4 = (const float4v*)feats;
    _Float16* pb = pos + n * CHW;
    _Float16* nb = neg + n * CHW;
    for (int j = tid; j < CHW/4; j += 256) {
        float4v ap = {0.f,0.f,0.f,0.f}, an = {0.f,0.f,0.f,0.f};
        for (int i = 0; i < m; ++i) {
            int v = lst[i];
            float4v x = f4[(v >> 1) * (CHW/4) + j];
            if (v & 1) ap += x; else an += x;
        }
        half4 sp, sn;
        #pragma unroll
        for (int r = 0; r < 4; ++r) { sp[r] = (_Float16)ap[r]; sn[r] = (_Float16)an[r]; }
        *(half4*)(pb + 4*j) = sp;
        *(half4*)(nb + 4*j) = sn;
    }
}

// ------------------------------------------------------- K2: fused 3-conv MFMA
__global__ __launch_bounds__(512, 2) void conv_kernel(
    const float* __restrict__ feats,
    const _Float16* __restrict__ pos, const _Float16* __restrict__ neg,
    const float* __restrict__ w1, const float* __restrict__ b1,
    const float* __restrict__ w2, const float* __restrict__ b2,
    const float* __restrict__ w3, const float* __restrict__ b3,
    float* __restrict__ out)
{
    __shared__ __align__(16) _Float16 Xs[XSZ];
    __shared__ __align__(16) _Float16 Ws[WSZ];
    const int n    = blockIdx.x;
    const int tid  = threadIdx.x;
    const int wave = tid >> 6;
    const int lane = tid & 63;
    const int col  = lane & 15;
    const int quad = lane >> 4;

    // phase 0: zero LDS (halo + K-pads must be 0)
    {
        int* xi = (int*)Xs;
        for (int i = tid; i < XSZ/2; i += 512) xi[i] = 0;
        int* wi = (int*)Ws;
        for (int i = tid; i < WSZ/2; i += 512) wi[i] = 0;
    }
    __syncthreads();

    // phase 1: stage X1 interior ([h+1][w+1][c] fp16; c: 0-15 feats,16-31 pos,32-47 neg) + W1
    {
        const float*    fb = feats + n * CHW;
        const _Float16* pp = pos   + n * CHW;
        const _Float16* qq = neg   + n * CHW;
        for (int i = tid; i < CHW; i += 512) {
            int c = i >> 10, p = i & 1023;
            int base = (((p >> 5) + 1) * 34 + (p & 31) + 1) * ICP1;
            Xs[base + c]      = (_Float16)fb[i];
            Xs[base + 16 + c] = pp[i];
            Xs[base + 32 + c] = qq[i];
        }
        // w1 OIHW (32,48,3,3): linear coalesced read, scatter to Ws[oc][tap*48+ic]
        for (int i = tid; i < 32*432; i += 512) {
            int oc = i / 432, r = i - oc*432;
            int ic = r / 9,   tap = r - ic*9;
            Ws[oc*KP1 + tap*48 + ic] = (_Float16)w1[i];
        }
    }
    __syncthreads();

    float4v acc[2][8];

    // conv1: M=32 (2 frags), N=1024 (8 waves x 8 frags of 16 px), K=432 (14 steps, zero-padded)
    {
        #pragma unroll
        for (int m = 0; m < 2; ++m)
            #pragma unroll
            for (int j = 0; j < 8; ++j) acc[m][j] = (float4v){0.f,0.f,0.f,0.f};
        int pixb[8];
        #pragma unroll
        for (int j = 0; j < 8; ++j) {
            int p = wave*128 + j*16 + col;
            pixb[j] = ((p >> 5)*34 + (p & 31)) * ICP1;
        }
        const int abase = col * KP1 + quad * 8;
        for (int ks = 0; ks < 14; ++ks) {
            int kq  = ks*32 + quad*8;
            int tap = kq / 48;
            int off = 0;                       // tap>=9: pad K-range; A is zero there, any finite B ok
            if (tap < 9) {
                int ic0 = kq - tap*48;
                int dh = tap / 3, dw = tap - dh*3;
                off = (dh*34 + dw)*ICP1 + ic0;
            }
            half8 a0 = *(const half8*)(Ws + abase + ks*32);
            half8 a1 = *(const half8*)(Ws + 16*KP1 + abase + ks*32);
            #pragma unroll
            for (int j = 0; j < 8; ++j) {
                half8 b = *(const half8*)(Xs + pixb[j] + off);
                acc[0][j] = __builtin_amdgcn_mfma_f32_16x16x32_f16(a0, b, acc[0][j], 0, 0, 0);
                acc[1][j] = __builtin_amdgcn_mfma_f32_16x16x32_f16(a1, b, acc[1][j], 0, 0, 0);
            }
        }
    }
    __syncthreads();

    // epilogue1: y1 = leaky(acc+b1) -> Ys (reuse Xs, [h][w][ICP2]); zero halo/pads; stage W2
    {
        for (int i = tid; i < 1156; i += 512) {       // 34x34 padded pixels
            int hp = i / 34, wp = i - hp*34;
            int* y = (int*)(Xs + i*ICP2);
            if (hp == 0 || hp == 33 || wp == 0 || wp == 33) {
                #pragma unroll
                for (int t = 0; t < ICP2/2; ++t) y[t] = 0;
            } else {
                y[16] = 0; y[17] = 0; y[18] = 0; y[19] = 0;   // ch pads [32,40)
            }
        }
        float bv[2][4];
        #pragma unroll
        for (int m = 0; m < 2; ++m)
            #pragma unroll
            for (int r = 0; r < 4; ++r) bv[m][r] = b1[m*16 + quad*4 + r];
        #pragma unroll
        for (int m = 0; m < 2; ++m)
            #pragma unroll
            for (int j = 0; j < 8; ++j) {
                int p = wave*128 + j*16 + col;
                _Float16* y = Xs + ((((p>>5)+1)*34) + (p&31) + 1)*ICP2 + m*16 + quad*4;
                half4 v;
                #pragma unroll
                for (int r = 0; r < 4; ++r) v[r] = (_Float16)leaky(acc[m][j][r] + bv[m][r]);
                *(half4*)y = v;
            }
        for (int i = tid; i < 32*288; i += 512) {
            int oc = i / 288, r = i - oc*288;
            int ic = r / 9,   tap = r - ic*9;
            Ws[oc*KP2 + tap*32 + ic] = (_Float16)w2[i];
        }
    }
    __syncthreads();

    // conv2: M=32, K=288 (9 steps exact)
    {
        #pragma unroll
        for (int m = 0; m < 2; ++m)
            #pragma unroll
            for (int j = 0; j < 8; ++j) acc[m][j] = (float4v){0.f,0.f,0.f,0.f};
        int pixb[8];
        #pragma unroll
        for (int j = 0; j < 8; ++j) {
            int p = wave*128 + j*16 + col;
            pixb[j] = ((p >> 5)*34 + (p & 31)) * ICP2;
        }
        const int abase = col * KP2 + quad * 8;
        for (int ks = 0; ks < 9; ++ks) {
            int kq  = ks*32 + quad*8;
            int tap = kq >> 5, ic0 = kq & 31;
            int dh = tap / 3, dw = tap - dh*3;
            int off = (dh*34 + dw)*ICP2 + ic0;
            half8 a0 = *(const half8*)(Ws + abase + ks*32);
            half8 a1 = *(const half8*)(Ws + 16*KP2 + abase + ks*32);
            #pragma unroll
            for (int j = 0; j < 8; ++j) {
                half8 b = *(const half8*)(Xs + pixb[j] + off);
                acc[0][j] = __builtin_amdgcn_mfma_f32_16x16x32_f16(a0, b, acc[0][j], 0, 0, 0);
                acc[1][j] = __builtin_amdgcn_mfma_f32_16x16x32_f16(a1, b, acc[1][j], 0, 0, 0);
            }
        }
    }
    __syncthreads();

    // epilogue2: y2 -> Ys interior (halo/pads still zero); stage W3
    {
        float bv[2][4];
        #pragma unroll
        for (int m = 0; m < 2; ++m)
            #pragma unroll
            for (int r = 0; r < 4; ++r) bv[m][r] = b2[m*16 + quad*4 + r];
        #pragma unroll
        for (int m = 0; m < 2; ++m)
            #pragma unroll
            for (int j = 0; j < 8; ++j) {
                int p = wave*128 + j*16 + col;
                _Float16* y = Xs + ((((p>>5)+1)*34) + (p&31) + 1)*ICP2 + m*16 + quad*4;
                half4 v;
                #pragma unroll
                for (int r = 0; r < 4; ++r) v[r] = (_Float16)leaky(acc[m][j][r] + bv[m][r]);
                *(half4*)y = v;
            }
        for (int i = tid; i < 16*288; i += 512) {
            int oc = i / 288, r = i - oc*288;
            int ic = r / 9,   tap = r - ic*9;
            Ws[oc*KP2 + tap*32 + ic] = (_Float16)w3[i];
        }
    }
    __syncthreads();

    // conv3: M=16 (1 frag), K=288; write fp32 out NCHW
    {
        float4v a3[8];
        #pragma unroll
        for (int j = 0; j < 8; ++j) a3[j] = (float4v){0.f,0.f,0.f,0.f};
        int pixb[8];
        #pragma unroll
        for (int j = 0; j < 8; ++j) {
            int p = wave*128 + j*16 + col;
            pixb[j] = ((p >> 5)*34 + (p & 31)) * ICP2;
        }
        const int abase = col * KP2 + quad * 8;
        for (int ks = 0; ks < 9; ++ks) {
            int kq  = ks*32 + quad*8;
            int tap = kq >> 5, ic0 = kq & 31;
            int dh = tap / 3, dw = tap - dh*3;
            int off = (dh*34 + dw)*ICP2 + ic0;
            half8 a0 = *(const half8*)(Ws + abase + ks*32);
            #pragma unroll
            for (int j = 0; j < 8; ++j) {
                half8 b = *(const half8*)(Xs + pixb[j] + off);
                a3[j] = __builtin_amdgcn_mfma_f32_16x16x32_f16(a0, b, a3[j], 0, 0, 0);
            }
        }
        float bv[4];
        #pragma unroll
        for (int r = 0; r < 4; ++r) bv[r] = b3[quad*4 + r];
        float* op = out + n * CHW;
        #pragma unroll
        for (int j = 0; j < 8; ++j) {
            int p = wave*128 + j*16 + col;
            #pragma unroll
            for (int r = 0; r < 4; ++r)
                op[(quad*4 + r)*1024 + p] = leaky(a3[j][r] + bv[r]);
        }
    }
}

extern "C" void kernel_launch(void* const* d_in, const int* in_sizes, int n_in,
                              void* d_out, int out_size, void* d_ws, size_t ws_size,
                              hipStream_t stream) {
    const float* feats = (const float*)d_in[0];
    const int*   edges = (const int*)  d_in[1];
    const float* w1 = (const float*)d_in[2];
    const float* b1 = (const float*)d_in[3];
    const float* w2 = (const float*)d_in[4];
    const float* b2 = (const float*)d_in[5];
    const float* w3 = (const float*)d_in[6];
    const float* b3 = (const float*)d_in[7];
    float* out = (float*)d_out;

    _Float16* pos = (_Float16*)d_ws;                   // 32 MiB
    _Float16* neg = pos + (size_t)NIMG * CHW;          // 32 MiB  (needs ws >= 64 MiB)

    pool_kernel<<<dim3(NIMG), dim3(256), 0, stream>>>(feats, edges, pos, neg);
    conv_kernel<<<dim3(NIMG), dim3(512), 0, stream>>>(feats, pos, neg,
                                                      w1, b1, w2, b2, w3, b3, out);
}

// Round 2
// 295.194 us; speedup vs baseline: 1.1271x; 1.1271x over previous
//
#include <hip/hip_runtime.h>

// Problem: N=1024 images of (16,32,32); E=4096 signed edges; pos/neg pooled by
// sign; concat -> 48ch; 3x (3x3 conv pad1 + leaky 0.1): 48->32->32->16.
//
// R2 design:
//  K1 pool_kernel: 2048 blocks = (node, half-image). Edge scan -> LDS adjacency;
//     gather nbr feats with 16 independent coalesced dword loads per nbr; fp32
//     accumulate; write pooled CHANNEL-LAST fp16 [n][p][32] (c<16 pos, c>=16 neg).
//     Finer blocks shrink the degree-tail critical path vs R1's 1 block/node.
//  K2 conv_kernel: 1 block (512 thr) per image, fully fused conv1/2/3 via
//     mfma_f32_16x16x32_f16. R2 staging: no full-LDS zero (only 132 halo px +
//     Ws1 K-pad; channel pads provably never read: ic0 in {0,8,..,40}, +8<=48);
//     pooled staged as b128 copies; feats transposed via float4 reads + packed
//     half2 b32 writes. LDS strides ICP1=56/KP1=456/ICP2=40/KP2=296 give
//     uniform bank coverage (verified: 256 dword-accesses/b128-wave = 8/bank).

#define NIMG 1024
#define CHW  16384      // 16*32*32
#define NEDGE 4096
#define MAXD 192

#define ICP1 56         // 48 ch padded; 112B stride: 16B-aligned
#define KP1  456        // K1=432 padded (reads reach 448); 912B stride
#define ICP2 40         // 32 ch padded; 80B stride
#define KP2  296
#define XSZ (34*34*ICP1)   // 64736 halves = 129472 B
#define WSZ (32*KP1)       // 14592 halves =  29184 B  (total 158656 B <= 160 KiB)

typedef __attribute__((ext_vector_type(8))) _Float16 half8;
typedef __attribute__((ext_vector_type(4))) _Float16 half4;
typedef __attribute__((ext_vector_type(2))) _Float16 half2;
typedef __attribute__((ext_vector_type(4))) float float4v;

__device__ __forceinline__ float leaky(float x) { return x > 0.f ? x : 0.1f * x; }

// ---------------------------------------------------------------- K1: pooling
// pooled[n][p][c]: c 0..15 = pos, 16..31 = neg. fp16, 64 B per pixel.
__global__ __launch_bounds__(256) void pool_kernel(
    const float* __restrict__ feats, const int* __restrict__ edges,
    _Float16* __restrict__ pooled)
{
    __shared__ int lst[MAXD];
    __shared__ int cnt;
    const int n    = blockIdx.x >> 1;
    const int half = blockIdx.x & 1;
    const int tid  = threadIdx.x;
    if (tid == 0) cnt = 0;
    __syncthreads();
    // dtype hedge: int64 layout => word[1] = high word of src0 = 0;
    // int32 layout => word[1] = sign0 = +-1 (never 0).
    const bool is64 = (edges[1] == 0);
    for (int e = tid; e < NEDGE; e += 256) {
        int s, sg, d;
        if (is64) { s = edges[6*e]; sg = edges[6*e + 2]; d = edges[6*e + 4]; }
        else      { s = edges[3*e]; sg = edges[3*e + 1]; d = edges[3*e + 2]; }
        if (s == n) { int i = atomicAdd(&cnt, 1); if (i < MAXD) lst[i] = (d << 1) | (int)(sg > 0); }
        if (d == n) { int i = atomicAdd(&cnt, 1); if (i < MAXD) lst[i] = (s << 1) | (int)(sg > 0); }
    }
    __syncthreads();
    int m = cnt; if (m > MAXD) m = MAXD;

    for (int it = 0; it < 2; ++it) {
        const int p = half*512 + it*256 + tid;          // pixel 0..1023
        float ap[16], an[16];
        #pragma unroll
        for (int c = 0; c < 16; ++c) { ap[c] = 0.f; an[c] = 0.f; }
        for (int i = 0; i < m; ++i) {
            const int v = lst[i];
            const float* fb = feats + (size_t)(v >> 1) * CHW + p;
            float t[16];
            #pragma unroll
            for (int c = 0; c < 16; ++c) t[c] = fb[c << 10];   // coalesced, independent
            if (v & 1) {
                #pragma unroll
                for (int c = 0; c < 16; ++c) ap[c] += t[c];
            } else {
                #pragma unroll
                for (int c = 0; c < 16; ++c) an[c] += t[c];
            }
        }
        _Float16* ob = pooled + ((size_t)n * 1024 + p) * 32;
        half8 v0, v1, v2, v3;
        #pragma unroll
        for (int c = 0; c < 8; ++c) { v0[c] = (_Float16)ap[c]; v1[c] = (_Float16)ap[c+8];
                                      v2[c] = (_Float16)an[c]; v3[c] = (_Float16)an[c+8]; }
        *(half8*)(ob)      = v0;
        *(half8*)(ob + 8)  = v1;
        *(half8*)(ob + 16) = v2;
        *(half8*)(ob + 24) = v3;
    }
}

// ------------------------------------------------------- K2: fused 3-conv MFMA
__global__ __launch_bounds__(512, 2) void conv_kernel(
    const float* __restrict__ feats,
    const _Float16* __restrict__ pooled,
    const float* __restrict__ w1, const float* __restrict__ b1,
    const float* __restrict__ w2, const float* __restrict__ b2,
    const float* __restrict__ w3, const float* __restrict__ b3,
    float* __restrict__ out)
{
    __shared__ __align__(16) _Float16 Xs[XSZ];
    __shared__ __align__(16) _Float16 Ws[WSZ];
    const int n    = blockIdx.x;
    const int tid  = threadIdx.x;
    const int wave = tid >> 6;
    const int lane = tid & 63;
    const int col  = lane & 15;
    const int quad = lane >> 4;

    // ---- phase 1: stage X1 ([h+1][w+1][c]: c0-15 feats, 16-47 pooled) + W1 + zeros
    {
        // feats transpose: 2048 tasks = (channel-pair c2<8, 4-px group g<256)
        const float4v* f4 = (const float4v*)(feats + (size_t)n * CHW);
        #pragma unroll
        for (int k = 0; k < 4; ++k) {
            int q  = tid + k*512;
            int c2 = q >> 8;
            int g  = q & 255;
            float4v A = f4[(2*c2)*256 + g];
            float4v B = f4[(2*c2+1)*256 + g];
            int h = g >> 3, w4 = (g & 7) * 4;           // p=4g never crosses a row
            int base = ((h + 1)*34 + w4 + 1) * ICP1 + 2*c2;
            #pragma unroll
            for (int r = 0; r < 4; ++r) {
                half2 v = { (_Float16)A[r], (_Float16)B[r] };
                *(half2*)(Xs + base + r*ICP1) = v;
            }
        }
        // pooled: 2 px per thread, 4 b128 each
        const half8* pl = (const half8*)(pooled + (size_t)n * 1024 * 32);
        #pragma unroll
        for (int it = 0; it < 2; ++it) {
            int p = tid + it*512;
            int base = (((p >> 5) + 1)*34 + (p & 31) + 1) * ICP1 + 16;
            #pragma unroll
            for (int t = 0; t < 4; ++t) {
                half8 v = pl[p*4 + t];
                *(half8*)(Xs + base + t*8) = v;
            }
        }
        // W1 scatter: OIHW (32,48,3,3) -> Ws[oc][tap*48+ic]
        for (int i = tid; i < 32*432; i += 512) {
            int oc = i / 432, r = i - oc*432;
            int ic = r / 9,   tap = r - ic*9;
            Ws[oc*KP1 + tap*48 + ic] = (_Float16)w1[i];
        }
        // halo zero (132 px, ch [0,48) only -- pads never read)
        if (tid < 132) {
            int hp, wp;
            if      (tid < 34)  { hp = 0;        wp = tid; }
            else if (tid < 68)  { hp = 33;       wp = tid - 34; }
            else if (tid < 100) { hp = tid - 67; wp = 0; }
            else                { hp = tid - 99; wp = 33; }
            int base = (hp*34 + wp) * ICP1;
            #pragma unroll
            for (int t = 0; t < 6; ++t) *(half8*)(Xs + base + t*8) = (half8)0;
        }
        // Ws1 K-pad zero: [432,456) per oc (A-reads reach 448)
        if (tid >= 160 && tid < 192) {
            int base = (tid - 160)*KP1 + 432;
            #pragma unroll
            for (int t = 0; t < 3; ++t) *(half8*)(Ws + base + t*8) = (half8)0;
        }
    }
    __syncthreads();

    float4v acc[2][8];

    // ---- conv1: M=32, N=1024 (8 waves x 8 frags), K=432 (14 steps, zero-padded)
    {
        #pragma unroll
        for (int m = 0; m < 2; ++m)
            #pragma unroll
            for (int j = 0; j < 8; ++j) acc[m][j] = (float4v){0.f,0.f,0.f,0.f};
        int pixb[8];
        #pragma unroll
        for (int j = 0; j < 8; ++j) {
            int p = wave*128 + j*16 + col;
            pixb[j] = ((p >> 5)*34 + (p & 31)) * ICP1;
        }
        const int abase = col * KP1 + quad * 8;
        for (int ks = 0; ks < 14; ++ks) {
            int kq  = ks*32 + quad*8;
            int tap = kq / 48;
            int off = 0;                       // tap>=9: A is zero, any finite B ok
            if (tap < 9) {
                int ic0 = kq - tap*48;
                int dh = tap / 3, dw = tap - dh*3;
                off = (dh*34 + dw)*ICP1 + ic0;
            }
            half8 a0 = *(const half8*)(Ws + abase + ks*32);
            half8 a1 = *(const half8*)(Ws + 16*KP1 + abase + ks*32);
            #pragma unroll
            for (int j = 0; j < 8; ++j) {
                half8 b = *(const half8*)(Xs + pixb[j] + off);
                acc[0][j] = __builtin_amdgcn_mfma_f32_16x16x32_f16(a0, b, acc[0][j], 0, 0, 0);
                acc[1][j] = __builtin_amdgcn_mfma_f32_16x16x32_f16(a1, b, acc[1][j], 0, 0, 0);
            }
        }
    }
    __syncthreads();

    // ---- epilogue1: y1 = leaky(acc+b1) -> Xs [hp][wp][ICP2]; halo zero; stage W2
    {
        if (tid < 132) {
            int hp, wp;
            if      (tid < 34)  { hp = 0;        wp = tid; }
            else if (tid < 68)  { hp = 33;       wp = tid - 34; }
            else if (tid < 100) { hp = tid - 67; wp = 0; }
            else                { hp = tid - 99; wp = 33; }
            int base = (hp*34 + wp) * ICP2;
            #pragma unroll
            for (int t = 0; t < 4; ++t) *(half8*)(Xs + base + t*8) = (half8)0;
        }
        float bv[2][4];
        #pragma unroll
        for (int m = 0; m < 2; ++m)
            #pragma unroll
            for (int r = 0; r < 4; ++r) bv[m][r] = b1[m*16 + quad*4 + r];
        #pragma unroll
        for (int m = 0; m < 2; ++m)
            #pragma unroll
            for (int j = 0; j < 8; ++j) {
                int p = wave*128 + j*16 + col;
                _Float16* y = Xs + ((((p>>5)+1)*34) + (p&31) + 1)*ICP2 + m*16 + quad*4;
                half4 v;
                #pragma unroll
                for (int r = 0; r < 4; ++r) v[r] = (_Float16)leaky(acc[m][j][r] + bv[m][r]);
                *(half4*)y = v;
            }
        for (int i = tid; i < 32*288; i += 512) {
            int oc = i / 288, r = i - oc*288;
            int ic = r / 9,   tap = r - ic*9;
            Ws[oc*KP2 + tap*32 + ic] = (_Float16)w2[i];
        }
    }
    __syncthreads();

    // ---- conv2: M=32, K=288 (9 steps exact)
    {
        #pragma unroll
        for (int m = 0; m < 2; ++m)
            #pragma unroll
            for (int j = 0; j < 8; ++j) acc[m][j] = (float4v){0.f,0.f,0.f,0.f};
        int pixb[8];
        #pragma unroll
        for (int j = 0; j < 8; ++j) {
            int p = wave*128 + j*16 + col;
            pixb[j] = ((p >> 5)*34 + (p & 31)) * ICP2;
        }
        const int abase = col * KP2 + quad * 8;
        for (int ks = 0; ks < 9; ++ks) {
            int kq  = ks*32 + quad*8;
            int tap = kq >> 5, ic0 = kq & 31;
            int dh = tap / 3, dw = tap - dh*3;
            int off = (dh*34 + dw)*ICP2 + ic0;
            half8 a0 = *(const half8*)(Ws + abase + ks*32);
            half8 a1 = *(const half8*)(Ws + 16*KP2 + abase + ks*32);
            #pragma unroll
            for (int j = 0; j < 8; ++j) {
                half8 b = *(const half8*)(Xs + pixb[j] + off);
                acc[0][j] = __builtin_amdgcn_mfma_f32_16x16x32_f16(a0, b, acc[0][j], 0, 0, 0);
                acc[1][j] = __builtin_amdgcn_mfma_f32_16x16x32_f16(a1, b, acc[1][j], 0, 0, 0);
            }
        }
    }
    __syncthreads();

    // ---- epilogue2: y2 -> Xs interior (halo still zero); stage W3
    {
        float bv[2][4];
        #pragma unroll
        for (int m = 0; m < 2; ++m)
            #pragma unroll
            for (int r = 0; r < 4; ++r) bv[m][r] = b2[m*16 + quad*4 + r];
        #pragma unroll
        for (int m = 0; m < 2; ++m)
            #pragma unroll
            for (int j = 0; j < 8; ++j) {
                int p = wave*128 + j*16 + col;
                _Float16* y = Xs + ((((p>>5)+1)*34) + (p&31) + 1)*ICP2 + m*16 + quad*4;
                half4 v;
                #pragma unroll
                for (int r = 0; r < 4; ++r) v[r] = (_Float16)leaky(acc[m][j][r] + bv[m][r]);
                *(half4*)y = v;
            }
        for (int i = tid; i < 16*288; i += 512) {
            int oc = i / 288, r = i - oc*288;
            int ic = r / 9,   tap = r - ic*9;
            Ws[oc*KP2 + tap*32 + ic] = (_Float16)w3[i];
        }
    }
    __syncthreads();

    // ---- conv3: M=16, K=288; fp32 NCHW out
    {
        float4v a3[8];
        #pragma unroll
        for (int j = 0; j < 8; ++j) a3[j] = (float4v){0.f,0.f,0.f,0.f};
        int pixb[8];
        #pragma unroll
        for (int j = 0; j < 8; ++j) {
            int p = wave*128 + j*16 + col;
            pixb[j] = ((p >> 5)*34 + (p & 31)) * ICP2;
        }
        const int abase = col * KP2 + quad * 8;
        for (int ks = 0; ks < 9; ++ks) {
            int kq  = ks*32 + quad*8;
            int tap = kq >> 5, ic0 = kq & 31;
            int dh = tap / 3, dw = tap - dh*3;
            int off = (dh*34 + dw)*ICP2 + ic0;
            half8 a0 = *(const half8*)(Ws + abase + ks*32);
            #pragma unroll
            for (int j = 0; j < 8; ++j) {
                half8 b = *(const half8*)(Xs + pixb[j] + off);
                a3[j] = __builtin_amdgcn_mfma_f32_16x16x32_f16(a0, b, a3[j], 0, 0, 0);
            }
        }
        float bv[4];
        #pragma unroll
        for (int r = 0; r < 4; ++r) bv[r] = b3[quad*4 + r];
        float* op = out + (size_t)n * CHW;
        #pragma unroll
        for (int j = 0; j < 8; ++j) {
            int p = wave*128 + j*16 + col;
            #pragma unroll
            for (int r = 0; r < 4; ++r)
                op[(quad*4 + r)*1024 + p] = leaky(a3[j][r] + bv[r]);
        }
    }
}

extern "C" void kernel_launch(void* const* d_in, const int* in_sizes, int n_in,
                              void* d_out, int out_size, void* d_ws, size_t ws_size,
                              hipStream_t stream) {
    const float* feats = (const float*)d_in[0];
    const int*   edges = (const int*)  d_in[1];
    const float* w1 = (const float*)d_in[2];
    const float* b1 = (const float*)d_in[3];
    const float* w2 = (const float*)d_in[4];
    const float* b2 = (const float*)d_in[5];
    const float* w3 = (const float*)d_in[6];
    const float* b3 = (const float*)d_in[7];
    float* out = (float*)d_out;

    _Float16* pooled = (_Float16*)d_ws;                // 64 MiB: [n][p][32] fp16

    pool_kernel<<<dim3(2*NIMG), dim3(256), 0, stream>>>(feats, edges, pooled);
    conv_kernel<<<dim3(NIMG), dim3(512), 0, stream>>>(feats, pooled,
                                                      w1, b1, w2, b2, w3, b3, out);
}

// Round 3
// 287.011 us; speedup vs baseline: 1.1592x; 1.0285x over previous
//
#include <hip/hip_runtime.h>

// N=1024 images (16,32,32); E=4096 signed edges; pos/neg pooled by sign;
// concat -> 48ch; 3x (3x3 conv pad1 + leaky 0.1): 48->32->32->16.
//
// R3 design:
//  K0 transpose_kernel: feats NCHW fp32 -> feats_cl[n][p][16] fp16 (32 MiB in
//     ws, after pooled). Enables 16B/lane gathers in pool and b128 staging in
//     conv (kills the 8-way-conflict fp32 transpose that cost ~25 us in R2).
//  K1 pool_kernel: 2048 blocks (node, half-image); edge scan -> LDS adjacency;
//     gather nbr pixels as 2x half8 loads (32 B/px vs 64 B + 16 insts in R2);
//     fp32 accumulate; write pooled[n][p][32] fp16.
//  K2 conv_kernel: 1 block/image, fused conv1/2/3 via mfma_f32_16x16x32_f16;
//     feats staged from feats_cl as b128 copies; ks loops fully unrolled.
//  Fallback (ws < 96 MiB): R2 paths (fp32 gathers + in-kernel transpose),
//     selected host-side on ws_size (constant per session -> graph-safe).

#define NIMG 1024
#define CHW  16384      // 16*32*32
#define NEDGE 4096
#define MAXD 192

#define ICP1 56         // 48 ch padded; 112B stride
#define KP1  456        // K1=432 padded (reads reach 448)
#define ICP2 40         // 32 ch padded; 80B stride
#define KP2  296
#define XSZ (34*34*ICP1)   // 129472 B
#define WSZ (32*KP1)       //  29184 B  (total 158656 B <= 160 KiB)

typedef __attribute__((ext_vector_type(8))) _Float16 half8;
typedef __attribute__((ext_vector_type(4))) _Float16 half4;
typedef __attribute__((ext_vector_type(2))) _Float16 half2;
typedef __attribute__((ext_vector_type(4))) float float4v;

__device__ __forceinline__ float leaky(float x) { return x > 0.f ? x : 0.1f * x; }

// ------------------------------------------------- K0: NCHW fp32 -> [p][16] fp16
__global__ __launch_bounds__(256) void transpose_kernel(
    const float* __restrict__ feats, _Float16* __restrict__ fcl)
{
    const int n = blockIdx.x, tid = threadIdx.x;
    const float* fb = feats + (size_t)n * CHW;
    _Float16*    ob = fcl   + (size_t)n * 1024 * 16;
    #pragma unroll
    for (int it = 0; it < 4; ++it) {
        int p = it*256 + tid;
        float t[16];
        #pragma unroll
        for (int c = 0; c < 16; ++c) t[c] = fb[(c << 10) + p];   // coalesced per ch
        half8 v0, v1;
        #pragma unroll
        for (int c = 0; c < 8; ++c) { v0[c] = (_Float16)t[c]; v1[c] = (_Float16)t[c+8]; }
        *(half8*)(ob + p*16)     = v0;
        *(half8*)(ob + p*16 + 8) = v1;
    }
}

// ---------------------------------------------------------------- K1: pooling
// pooled[n][p][c]: c 0..15 = pos, 16..31 = neg. fp16, 64 B per pixel.
__global__ __launch_bounds__(256) void pool_kernel(
    const float* __restrict__ feats, const int* __restrict__ edges,
    _Float16* __restrict__ pooled, const _Float16* __restrict__ fcl, int use_fcl)
{
    __shared__ int lst[MAXD];
    __shared__ int cnt;
    const int n    = blockIdx.x >> 1;
    const int half = blockIdx.x & 1;
    const int tid  = threadIdx.x;
    if (tid == 0) cnt = 0;
    __syncthreads();
    // dtype hedge: int64 layout => word[1] = high word of src0 = 0;
    // int32 layout => word[1] = sign0 = +-1 (never 0).
    const bool is64 = (edges[1] == 0);
    for (int e = tid; e < NEDGE; e += 256) {
        int s, sg, d;
        if (is64) { s = edges[6*e]; sg = edges[6*e + 2]; d = edges[6*e + 4]; }
        else      { s = edges[3*e]; sg = edges[3*e + 1]; d = edges[3*e + 2]; }
        if (s == n) { int i = atomicAdd(&cnt, 1); if (i < MAXD) lst[i] = (d << 1) | (int)(sg > 0); }
        if (d == n) { int i = atomicAdd(&cnt, 1); if (i < MAXD) lst[i] = (s << 1) | (int)(sg > 0); }
    }
    __syncthreads();
    int m = cnt; if (m > MAXD) m = MAXD;

    for (int it = 0; it < 2; ++it) {
        const int p = half*512 + it*256 + tid;          // pixel 0..1023
        float ap[16], an[16];
        #pragma unroll
        for (int c = 0; c < 16; ++c) { ap[c] = 0.f; an[c] = 0.f; }
        if (use_fcl) {
            for (int i = 0; i < m; ++i) {
                const int v = lst[i];
                const half8* fb = (const half8*)(fcl + (size_t)(v >> 1) * CHW);
                half8 x0 = fb[2*p], x1 = fb[2*p + 1];    // 32 B/lane, fully coalesced
                if (v & 1) {
                    #pragma unroll
                    for (int c = 0; c < 8; ++c) { ap[c] += (float)x0[c]; ap[c+8] += (float)x1[c]; }
                } else {
                    #pragma unroll
                    for (int c = 0; c < 8; ++c) { an[c] += (float)x0[c]; an[c+8] += (float)x1[c]; }
                }
            }
        } else {
            for (int i = 0; i < m; ++i) {
                const int v = lst[i];
                const float* fb = feats + (size_t)(v >> 1) * CHW + p;
                float t[16];
                #pragma unroll
                for (int c = 0; c < 16; ++c) t[c] = fb[c << 10];
                if (v & 1) {
                    #pragma unroll
                    for (int c = 0; c < 16; ++c) ap[c] += t[c];
                } else {
                    #pragma unroll
                    for (int c = 0; c < 16; ++c) an[c] += t[c];
                }
            }
        }
        _Float16* ob = pooled + ((size_t)n * 1024 + p) * 32;
        half8 v0, v1, v2, v3;
        #pragma unroll
        for (int c = 0; c < 8; ++c) { v0[c] = (_Float16)ap[c]; v1[c] = (_Float16)ap[c+8];
                                      v2[c] = (_Float16)an[c]; v3[c] = (_Float16)an[c+8]; }
        *(half8*)(ob)      = v0;
        *(half8*)(ob + 8)  = v1;
        *(half8*)(ob + 16) = v2;
        *(half8*)(ob + 24) = v3;
    }
}

// ------------------------------------------------------- K2: fused 3-conv MFMA
__global__ __launch_bounds__(512, 2) void conv_kernel(
    const float* __restrict__ feats,
    const _Float16* __restrict__ pooled,
    const _Float16* __restrict__ fcl, int use_fcl,
    const float* __restrict__ w1, const float* __restrict__ b1,
    const float* __restrict__ w2, const float* __restrict__ b2,
    const float* __restrict__ w3, const float* __restrict__ b3,
    float* __restrict__ out)
{
    __shared__ __align__(16) _Float16 Xs[XSZ];
    __shared__ __align__(16) _Float16 Ws[WSZ];
    const int n    = blockIdx.x;
    const int tid  = threadIdx.x;
    const int wave = tid >> 6;
    const int lane = tid & 63;
    const int col  = lane & 15;
    const int quad = lane >> 4;

    // ---- phase 1: stage X1 ([h+1][w+1][c]: c0-15 feats, 16-47 pooled) + W1 + zeros
    {
        if (use_fcl) {
            const half8* fc = (const half8*)(fcl    + (size_t)n * CHW);
            const half8* pl = (const half8*)(pooled + (size_t)n * 1024 * 32);
            #pragma unroll
            for (int it = 0; it < 2; ++it) {
                int p = tid + it*512;
                int base = (((p >> 5) + 1)*34 + (p & 31) + 1) * ICP1;
                *(half8*)(Xs + base)     = fc[2*p];
                *(half8*)(Xs + base + 8) = fc[2*p + 1];
                #pragma unroll
                for (int t = 0; t < 4; ++t)
                    *(half8*)(Xs + base + 16 + t*8) = pl[p*4 + t];
            }
        } else {
            // fp32 transpose fallback (R2 path)
            const float4v* f4 = (const float4v*)(feats + (size_t)n * CHW);
            #pragma unroll
            for (int k = 0; k < 4; ++k) {
                int q  = tid + k*512;
                int c2 = q >> 8;
                int g  = q & 255;
                float4v A = f4[(2*c2)*256 + g];
                float4v B = f4[(2*c2+1)*256 + g];
                int h = g >> 3, w4 = (g & 7) * 4;
                int base = ((h + 1)*34 + w4 + 1) * ICP1 + 2*c2;
                #pragma unroll
                for (int r = 0; r < 4; ++r) {
                    half2 v = { (_Float16)A[r], (_Float16)B[r] };
                    *(half2*)(Xs + base + r*ICP1) = v;
                }
            }
            const half8* pl = (const half8*)(pooled + (size_t)n * 1024 * 32);
            #pragma unroll
            for (int it = 0; it < 2; ++it) {
                int p = tid + it*512;
                int base = (((p >> 5) + 1)*34 + (p & 31) + 1) * ICP1 + 16;
                #pragma unroll
                for (int t = 0; t < 4; ++t)
                    *(half8*)(Xs + base + t*8) = pl[p*4 + t];
            }
        }
        // W1 scatter: OIHW (32,48,3,3) -> Ws[oc][tap*48+ic]
        for (int i = tid; i < 32*432; i += 512) {
            int oc = i / 432, r = i - oc*432;
            int ic = r / 9,   tap = r - ic*9;
            Ws[oc*KP1 + tap*48 + ic] = (_Float16)w1[i];
        }
        // halo zero (132 px)
        if (tid < 132) {
            int hp, wp;
            if      (tid < 34)  { hp = 0;        wp = tid; }
            else if (tid < 68)  { hp = 33;       wp = tid - 34; }
            else if (tid < 100) { hp = tid - 67; wp = 0; }
            else                { hp = tid - 99; wp = 33; }
            int base = (hp*34 + wp) * ICP1;
            #pragma unroll
            for (int t = 0; t < 6; ++t) *(half8*)(Xs + base + t*8) = (half8)0;
        }
        // Ws1 K-pad zero: [432,456) per oc (A-reads reach 448)
        if (tid >= 160 && tid < 192) {
            int base = (tid - 160)*KP1 + 432;
            #pragma unroll
            for (int t = 0; t < 3; ++t) *(half8*)(Ws + base + t*8) = (half8)0;
        }
    }
    __syncthreads();

    float4v acc[2][8];

    // ---- conv1: M=32, N=1024 (8 waves x 8 frags), K=432 (14 steps, zero-padded)
    {
        #pragma unroll
        for (int m = 0; m < 2; ++m)
            #pragma unroll
            for (int j = 0; j < 8; ++j) acc[m][j] = (float4v){0.f,0.f,0.f,0.f};
        int pixb[8];
        #pragma unroll
        for (int j = 0; j < 8; ++j) {
            int p = wave*128 + j*16 + col;
            pixb[j] = ((p >> 5)*34 + (p & 31)) * ICP1;
        }
        const int abase = col * KP1 + quad * 8;
        #pragma unroll
        for (int ks = 0; ks < 14; ++ks) {
            int kq  = ks*32 + quad*8;
            int tap = kq / 48;
            int off = 0;                       // tap>=9: A is zero, any finite B ok
            if (tap < 9) {
                int ic0 = kq - tap*48;
                int dh = tap / 3, dw = tap - dh*3;
                off = (dh*34 + dw)*ICP1 + ic0;
            }
            half8 a0 = *(const half8*)(Ws + abase + ks*32);
            half8 a1 = *(const half8*)(Ws + 16*KP1 + abase + ks*32);
            #pragma unroll
            for (int j = 0; j < 8; ++j) {
                half8 b = *(const half8*)(Xs + pixb[j] + off);
                acc[0][j] = __builtin_amdgcn_mfma_f32_16x16x32_f16(a0, b, acc[0][j], 0, 0, 0);
                acc[1][j] = __builtin_amdgcn_mfma_f32_16x16x32_f16(a1, b, acc[1][j], 0, 0, 0);
            }
        }
    }
    __syncthreads();

    // ---- epilogue1: y1 = leaky(acc+b1) -> Xs [hp][wp][ICP2]; halo zero; stage W2
    {
        if (tid < 132) {
            int hp, wp;
            if      (tid < 34)  { hp = 0;        wp = tid; }
            else if (tid < 68)  { hp = 33;       wp = tid - 34; }
            else if (tid < 100) { hp = tid - 67; wp = 0; }
            else                { hp = tid - 99; wp = 33; }
            int base = (hp*34 + wp) * ICP2;
            #pragma unroll
            for (int t = 0; t < 4; ++t) *(half8*)(Xs + base + t*8) = (half8)0;
        }
        float bv[2][4];
        #pragma unroll
        for (int m = 0; m < 2; ++m)
            #pragma unroll
            for (int r = 0; r < 4; ++r) bv[m][r] = b1[m*16 + quad*4 + r];
        #pragma unroll
        for (int m = 0; m < 2; ++m)
            #pragma unroll
            for (int j = 0; j < 8; ++j) {
                int p = wave*128 + j*16 + col;
                _Float16* y = Xs + ((((p>>5)+1)*34) + (p&31) + 1)*ICP2 + m*16 + quad*4;
                half4 v;
                #pragma unroll
                for (int r = 0; r < 4; ++r) v[r] = (_Float16)leaky(acc[m][j][r] + bv[m][r]);
                *(half4*)y = v;
            }
        for (int i = tid; i < 32*288; i += 512) {
            int oc = i / 288, r = i - oc*288;
            int ic = r / 9,   tap = r - ic*9;
            Ws[oc*KP2 + tap*32 + ic] = (_Float16)w2[i];
        }
    }
    __syncthreads();

    // ---- conv2: M=32, K=288 (9 steps exact)
    {
        #pragma unroll
        for (int m = 0; m < 2; ++m)
            #pragma unroll
            for (int j = 0; j < 8; ++j) acc[m][j] = (float4v){0.f,0.f,0.f,0.f};
        int pixb[8];
        #pragma unroll
        for (int j = 0; j < 8; ++j) {
            int p = wave*128 + j*16 + col;
            pixb[j] = ((p >> 5)*34 + (p & 31)) * ICP2;
        }
        const int abase = col * KP2 + quad * 8;
        #pragma unroll
        for (int ks = 0; ks < 9; ++ks) {
            int kq  = ks*32 + quad*8;
            int tap = kq >> 5, ic0 = kq & 31;
            int dh = tap / 3, dw = tap - dh*3;
            int off = (dh*34 + dw)*ICP2 + ic0;
            half8 a0 = *(const half8*)(Ws + abase + ks*32);
            half8 a1 = *(const half8*)(Ws + 16*KP2 + abase + ks*32);
            #pragma unroll
            for (int j = 0; j < 8; ++j) {
                half8 b = *(const half8*)(Xs + pixb[j] + off);
                acc[0][j] = __builtin_amdgcn_mfma_f32_16x16x32_f16(a0, b, acc[0][j], 0, 0, 0);
                acc[1][j] = __builtin_amdgcn_mfma_f32_16x16x32_f16(a1, b, acc[1][j], 0, 0, 0);
            }
        }
    }
    __syncthreads();

    // ---- epilogue2: y2 -> Xs interior (halo still zero); stage W3
    {
        float bv[2][4];
        #pragma unroll
        for (int m = 0; m < 2; ++m)
            #pragma unroll
            for (int r = 0; r < 4; ++r) bv[m][r] = b2[m*16 + quad*4 + r];
        #pragma unroll
        for (int m = 0; m < 2; ++m)
            #pragma unroll
            for (int j = 0; j < 8; ++j) {
                int p = wave*128 + j*16 + col;
                _Float16* y = Xs + ((((p>>5)+1)*34) + (p&31) + 1)*ICP2 + m*16 + quad*4;
                half4 v;
                #pragma unroll
                for (int r = 0; r < 4; ++r) v[r] = (_Float16)leaky(acc[m][j][r] + bv[m][r]);
                *(half4*)y = v;
            }
        for (int i = tid; i < 16*288; i += 512) {
            int oc = i / 288, r = i - oc*288;
            int ic = r / 9,   tap = r - ic*9;
            Ws[oc*KP2 + tap*32 + ic] = (_Float16)w3[i];
        }
    }
    __syncthreads();

    // ---- conv3: M=16, K=288; fp32 NCHW out
    {
        float4v a3[8];
        #pragma unroll
        for (int j = 0; j < 8; ++j) a3[j] = (float4v){0.f,0.f,0.f,0.f};
        int pixb[8];
        #pragma unroll
        for (int j = 0; j < 8; ++j) {
            int p = wave*128 + j*16 + col;
            pixb[j] = ((p >> 5)*34 + (p & 31)) * ICP2;
        }
        const int abase = col * KP2 + quad * 8;
        #pragma unroll
        for (int ks = 0; ks < 9; ++ks) {
            int kq  = ks*32 + quad*8;
            int tap = kq >> 5, ic0 = kq & 31;
            int dh = tap / 3, dw = tap - dh*3;
            int off = (dh*34 + dw)*ICP2 + ic0;
            half8 a0 = *(const half8*)(Ws + abase + ks*32);
            #pragma unroll
            for (int j = 0; j < 8; ++j) {
                half8 b = *(const half8*)(Xs + pixb[j] + off);
                a3[j] = __builtin_amdgcn_mfma_f32_16x16x32_f16(a0, b, a3[j], 0, 0, 0);
            }
        }
        float bv[4];
        #pragma unroll
        for (int r = 0; r < 4; ++r) bv[r] = b3[quad*4 + r];
        float* op = out + (size_t)n * CHW;
        #pragma unroll
        for (int j = 0; j < 8; ++j) {
            int p = wave*128 + j*16 + col;
            #pragma unroll
            for (int r = 0; r < 4; ++r)
                op[(quad*4 + r)*1024 + p] = leaky(a3[j][r] + bv[r]);
        }
    }
}

extern "C" void kernel_launch(void* const* d_in, const int* in_sizes, int n_in,
                              void* d_out, int out_size, void* d_ws, size_t ws_size,
                              hipStream_t stream) {
    const float* feats = (const float*)d_in[0];
    const int*   edges = (const int*)  d_in[1];
    const float* w1 = (const float*)d_in[2];
    const float* b1 = (const float*)d_in[3];
    const float* w2 = (const float*)d_in[4];
    const float* b2 = (const float*)d_in[5];
    const float* w3 = (const float*)d_in[6];
    const float* b3 = (const float*)d_in[7];
    float* out = (float*)d_out;

    _Float16* pooled = (_Float16*)d_ws;                         // 64 MiB
    const int big = (ws_size >= (size_t)100663296) ? 1 : 0;     // need 96 MiB
    _Float16* fcl = big ? (_Float16*)((char*)d_ws + (64u << 20)) : (_Float16*)nullptr;

    if (big)
        transpose_kernel<<<dim3(NIMG), dim3(256), 0, stream>>>(feats, fcl);
    pool_kernel<<<dim3(2*NIMG), dim3(256), 0, stream>>>(feats, edges, pooled, fcl, big);
    conv_kernel<<<dim3(NIMG), dim3(512), 0, stream>>>(feats, pooled, fcl, big,
                                                      w1, b1, w2, b2, w3, b3, out);
}

// Round 4
// 249.308 us; speedup vs baseline: 1.3345x; 1.1512x over previous
//
#include <hip/hip_runtime.h>

// N=1024 images (16,32,32); E=4096 signed edges; pos/neg pooled by sign;
// concat -> 48ch; 3x (3x3 conv pad1 + leaky 0.1): 48->32->32->16.
//
// R4 design:
//  memset deg=0 (hipMemsetAsync, graph-safe)
//  K_adj  build_adj: 16 blocks scan 4096 edges ONCE -> deg[n], adj[n][64]
//         (R1-R3 had every pool block rescan all edges: the invariant ~150us).
//  K_t    transpose: feats NCHW fp32 -> fcl[n][p][16] fp16 (32 MiB in ws).
//  K_conv 1024 blocks x 1024 thr (16 waves: 4 waves/SIMD vs R3's 2 -- hides
//         LDS latency + barrier drains). Pooling FUSED into staging: each
//         thread owns 1 px, gathers <=64 nbrs from fcl (2x b128, wave-uniform
//         adj via s_load, uniform sign branch), fp32 accum, writes Xs ch16-47.
//         Then fused conv1/2/3 via mfma_f32_16x16x32_f16 (layouts verified
//         R1-R3), y1/y2 LDS-only. No pooled HBM round-trip (saves 128 MiB).
//  ws: fcl 32 MiB + deg 4 KB + adj 256 KB (< 64 MiB proven available).

#define NIMG 1024
#define CHW  16384      // 16*32*32
#define NEDGE 4096
#define MAXD 64

#define ICP1 56         // 48 ch padded; 112B stride (bank-even for b128)
#define KP1  456        // K1=432 padded (A-reads reach 448)
#define ICP2 40         // 32 ch padded; 80B stride
#define KP2  296
#define XSZ (34*34*ICP1)   // 129472 B
#define WSZ (32*KP1)       //  29184 B  (total 158656 B <= 160 KiB)

typedef __attribute__((ext_vector_type(8))) _Float16 half8;
typedef __attribute__((ext_vector_type(4))) _Float16 half4;
typedef __attribute__((ext_vector_type(4))) float float4v;

__device__ __forceinline__ float leaky(float x) { return x > 0.f ? x : 0.1f * x; }

// ----------------------------------------------------------- K_adj: adjacency
__global__ __launch_bounds__(256) void build_adj(
    const int* __restrict__ edges, int* __restrict__ deg, int* __restrict__ adj)
{
    const int e = blockIdx.x * 256 + threadIdx.x;   // 16 blocks x 256 = 4096
    // dtype hedge: int64 layout => word[1] = high word of src0 = 0;
    // int32 layout => word[1] = sign0 = +-1 (never 0).
    const bool is64 = (edges[1] == 0);
    int s, sg, d;
    if (is64) { s = edges[6*e]; sg = edges[6*e + 2]; d = edges[6*e + 4]; }
    else      { s = edges[3*e]; sg = edges[3*e + 1]; d = edges[3*e + 2]; }
    const int tag_d = (d << 1) | (int)(sg > 0);
    const int tag_s = (s << 1) | (int)(sg > 0);
    int i = atomicAdd(&deg[s], 1); if (i < MAXD) adj[(s << 6) + i] = tag_d;
    int j = atomicAdd(&deg[d], 1); if (j < MAXD) adj[(d << 6) + j] = tag_s;
}

// ------------------------------------------------- K_t: NCHW fp32 -> [p][16] fp16
__global__ __launch_bounds__(256) void transpose_kernel(
    const float* __restrict__ feats, _Float16* __restrict__ fcl)
{
    const int n = blockIdx.x, tid = threadIdx.x;
    const float* fb = feats + (size_t)n * CHW;
    _Float16*    ob = fcl   + (size_t)n * 1024 * 16;
    #pragma unroll
    for (int it = 0; it < 4; ++it) {
        int p = it*256 + tid;
        float t[16];
        #pragma unroll
        for (int c = 0; c < 16; ++c) t[c] = fb[(c << 10) + p];   // coalesced per ch
        half8 v0, v1;
        #pragma unroll
        for (int c = 0; c < 8; ++c) { v0[c] = (_Float16)t[c]; v1[c] = (_Float16)t[c+8]; }
        *(half8*)(ob + p*16)     = v0;
        *(half8*)(ob + p*16 + 8) = v1;
    }
}

// ------------------------------------- K_conv: fused pool-stage + 3-conv MFMA
__global__ __launch_bounds__(1024, 4) void conv_kernel(
    const _Float16* __restrict__ fcl,
    const int* __restrict__ deg, const int* __restrict__ adj,
    const float* __restrict__ w1, const float* __restrict__ b1,
    const float* __restrict__ w2, const float* __restrict__ b2,
    const float* __restrict__ w3, const float* __restrict__ b3,
    float* __restrict__ out)
{
    __shared__ __align__(16) _Float16 Xs[XSZ];
    __shared__ __align__(16) _Float16 Ws[WSZ];
    const int n    = blockIdx.x;
    const int tid  = threadIdx.x;
    const int wave = tid >> 6;
    const int lane = tid & 63;
    const int col  = lane & 15;
    const int quad = lane >> 4;

    // ---- phase 1: self-stage + fused pooling gather + W1 + zeros
    {
        const half8* fc = (const half8*)(fcl + (size_t)n * CHW);
        const int p = tid;                                    // 1 px per thread
        const int base = (((p >> 5) + 1)*34 + (p & 31) + 1) * ICP1;
        *(half8*)(Xs + base)     = fc[2*p];
        *(half8*)(Xs + base + 8) = fc[2*p + 1];

        int m = deg[n]; if (m > MAXD) m = MAXD;               // wave-uniform
        const int* al = adj + (n << 6);                       // uniform -> s_load
        float ap[16], an[16];
        #pragma unroll
        for (int c = 0; c < 16; ++c) { ap[c] = 0.f; an[c] = 0.f; }
        for (int i = 0; i < m; ++i) {
            const int v = al[i];
            const half8* fb = (const half8*)(fcl + (size_t)(v >> 1) * CHW);
            half8 x0 = fb[2*p], x1 = fb[2*p + 1];             // coalesced b128
            if (v & 1) {                                      // uniform branch
                #pragma unroll
                for (int c = 0; c < 8; ++c) { ap[c] += (float)x0[c]; ap[c+8] += (float)x1[c]; }
            } else {
                #pragma unroll
                for (int c = 0; c < 8; ++c) { an[c] += (float)x0[c]; an[c+8] += (float)x1[c]; }
            }
        }
        half8 h0, h1, h2, h3;
        #pragma unroll
        for (int c = 0; c < 8; ++c) { h0[c] = (_Float16)ap[c]; h1[c] = (_Float16)ap[c+8];
                                      h2[c] = (_Float16)an[c]; h3[c] = (_Float16)an[c+8]; }
        *(half8*)(Xs + base + 16) = h0;
        *(half8*)(Xs + base + 24) = h1;
        *(half8*)(Xs + base + 32) = h2;
        *(half8*)(Xs + base + 40) = h3;

        // W1 scatter: OIHW (32,48,3,3) -> Ws[oc][tap*48+ic]
        for (int i = tid; i < 32*432; i += 1024) {
            int oc = i / 432, r = i - oc*432;
            int ic = r / 9,   tap = r - ic*9;
            Ws[oc*KP1 + tap*48 + ic] = (_Float16)w1[i];
        }
        // halo zero (132 px, 48 ch)
        if (tid < 132) {
            int hp, wp;
            if      (tid < 34)  { hp = 0;        wp = tid; }
            else if (tid < 68)  { hp = 33;       wp = tid - 34; }
            else if (tid < 100) { hp = tid - 67; wp = 0; }
            else                { hp = tid - 99; wp = 33; }
            int hb = (hp*34 + wp) * ICP1;
            #pragma unroll
            for (int t = 0; t < 6; ++t) *(half8*)(Xs + hb + t*8) = (half8)0;
        }
        // Ws1 K-pad zero: [432,456) per oc (A-reads reach 448)
        if (tid >= 160 && tid < 192) {
            int wb = (tid - 160)*KP1 + 432;
            #pragma unroll
            for (int t = 0; t < 3; ++t) *(half8*)(Ws + wb + t*8) = (half8)0;
        }
    }
    __syncthreads();

    float4v acc[2][4];

    // ---- conv1: M=32, N=1024 (16 waves x 4 frags), K=432 (14 steps, zero-padded)
    {
        #pragma unroll
        for (int m = 0; m < 2; ++m)
            #pragma unroll
            for (int j = 0; j < 4; ++j) acc[m][j] = (float4v){0.f,0.f,0.f,0.f};
        int pixb[4];
        #pragma unroll
        for (int j = 0; j < 4; ++j) {
            int p = wave*64 + j*16 + col;
            pixb[j] = ((p >> 5)*34 + (p & 31)) * ICP1;
        }
        const int abase = col * KP1 + quad * 8;
        #pragma unroll
        for (int ks = 0; ks < 14; ++ks) {
            int kq  = ks*32 + quad*8;
            int tap = kq / 48;
            int off = 0;                       // tap>=9: A is zero, any finite B ok
            if (tap < 9) {
                int ic0 = kq - tap*48;
                int dh = tap / 3, dw = tap - dh*3;
                off = (dh*34 + dw)*ICP1 + ic0;
            }
            half8 a0 = *(const half8*)(Ws + abase + ks*32);
            half8 a1 = *(const half8*)(Ws + 16*KP1 + abase + ks*32);
            #pragma unroll
            for (int j = 0; j < 4; ++j) {
                half8 b = *(const half8*)(Xs + pixb[j] + off);
                acc[0][j] = __builtin_amdgcn_mfma_f32_16x16x32_f16(a0, b, acc[0][j], 0, 0, 0);
                acc[1][j] = __builtin_amdgcn_mfma_f32_16x16x32_f16(a1, b, acc[1][j], 0, 0, 0);
            }
        }
    }
    __syncthreads();

    // ---- epilogue1: y1 = leaky(acc+b1) -> Xs [hp][wp][ICP2]; halo zero; stage W2
    {
        if (tid < 132) {
            int hp, wp;
            if      (tid < 34)  { hp = 0;        wp = tid; }
            else if (tid < 68)  { hp = 33;       wp = tid - 34; }
            else if (tid < 100) { hp = tid - 67; wp = 0; }
            else                { hp = tid - 99; wp = 33; }
            int hb = (hp*34 + wp) * ICP2;
            #pragma unroll
            for (int t = 0; t < 4; ++t) *(half8*)(Xs + hb + t*8) = (half8)0;
        }
        float bv[2][4];
        #pragma unroll
        for (int m = 0; m < 2; ++m)
            #pragma unroll
            for (int r = 0; r < 4; ++r) bv[m][r] = b1[m*16 + quad*4 + r];
        #pragma unroll
        for (int m = 0; m < 2; ++m)
            #pragma unroll
            for (int j = 0; j < 4; ++j) {
                int p = wave*64 + j*16 + col;
                _Float16* y = Xs + ((((p>>5)+1)*34) + (p&31) + 1)*ICP2 + m*16 + quad*4;
                half4 v;
                #pragma unroll
                for (int r = 0; r < 4; ++r) v[r] = (_Float16)leaky(acc[m][j][r] + bv[m][r]);
                *(half4*)y = v;
            }
        for (int i = tid; i < 32*288; i += 1024) {
            int oc = i / 288, r = i - oc*288;
            int ic = r / 9,   tap = r - ic*9;
            Ws[oc*KP2 + tap*32 + ic] = (_Float16)w2[i];
        }
    }
    __syncthreads();

    // ---- conv2: M=32, K=288 (9 steps exact)
    {
        #pragma unroll
        for (int m = 0; m < 2; ++m)
            #pragma unroll
            for (int j = 0; j < 4; ++j) acc[m][j] = (float4v){0.f,0.f,0.f,0.f};
        int pixb[4];
        #pragma unroll
        for (int j = 0; j < 4; ++j) {
            int p = wave*64 + j*16 + col;
            pixb[j] = ((p >> 5)*34 + (p & 31)) * ICP2;
        }
        const int abase = col * KP2 + quad * 8;
        #pragma unroll
        for (int ks = 0; ks < 9; ++ks) {
            int kq  = ks*32 + quad*8;
            int tap = kq >> 5, ic0 = kq & 31;
            int dh = tap / 3, dw = tap - dh*3;
            int off = (dh*34 + dw)*ICP2 + ic0;
            half8 a0 = *(const half8*)(Ws + abase + ks*32);
            half8 a1 = *(const half8*)(Ws + 16*KP2 + abase + ks*32);
            #pragma unroll
            for (int j = 0; j < 4; ++j) {
                half8 b = *(const half8*)(Xs + pixb[j] + off);
                acc[0][j] = __builtin_amdgcn_mfma_f32_16x16x32_f16(a0, b, acc[0][j], 0, 0, 0);
                acc[1][j] = __builtin_amdgcn_mfma_f32_16x16x32_f16(a1, b, acc[1][j], 0, 0, 0);
            }
        }
    }
    __syncthreads();

    // ---- epilogue2: y2 -> Xs interior (halo still zero); stage W3
    {
        float bv[2][4];
        #pragma unroll
        for (int m = 0; m < 2; ++m)
            #pragma unroll
            for (int r = 0; r < 4; ++r) bv[m][r] = b2[m*16 + quad*4 + r];
        #pragma unroll
        for (int m = 0; m < 2; ++m)
            #pragma unroll
            for (int j = 0; j < 4; ++j) {
                int p = wave*64 + j*16 + col;
                _Float16* y = Xs + ((((p>>5)+1)*34) + (p&31) + 1)*ICP2 + m*16 + quad*4;
                half4 v;
                #pragma unroll
                for (int r = 0; r < 4; ++r) v[r] = (_Float16)leaky(acc[m][j][r] + bv[m][r]);
                *(half4*)y = v;
            }
        for (int i = tid; i < 16*288; i += 1024) {
            int oc = i / 288, r = i - oc*288;
            int ic = r / 9,   tap = r - ic*9;
            Ws[oc*KP2 + tap*32 + ic] = (_Float16)w3[i];
        }
    }
    __syncthreads();

    // ---- conv3: M=16, K=288; fp32 NCHW out
    {
        float4v a3[4];
        #pragma unroll
        for (int j = 0; j < 4; ++j) a3[j] = (float4v){0.f,0.f,0.f,0.f};
        int pixb[4];
        #pragma unroll
        for (int j = 0; j < 4; ++j) {
            int p = wave*64 + j*16 + col;
            pixb[j] = ((p >> 5)*34 + (p & 31)) * ICP2;
        }
        const int abase = col * KP2 + quad * 8;
        #pragma unroll
        for (int ks = 0; ks < 9; ++ks) {
            int kq  = ks*32 + quad*8;
            int tap = kq >> 5, ic0 = kq & 31;
            int dh = tap / 3, dw = tap - dh*3;
            int off = (dh*34 + dw)*ICP2 + ic0;
            half8 a0 = *(const half8*)(Ws + abase + ks*32);
            #pragma unroll
            for (int j = 0; j < 4; ++j) {
                half8 b = *(const half8*)(Xs + pixb[j] + off);
                a3[j] = __builtin_amdgcn_mfma_f32_16x16x32_f16(a0, b, a3[j], 0, 0, 0);
            }
        }
        float bv[4];
        #pragma unroll
        for (int r = 0; r < 4; ++r) bv[r] = b3[quad*4 + r];
        float* op = out + (size_t)n * CHW;
        #pragma unroll
        for (int j = 0; j < 4; ++j) {
            int p = wave*64 + j*16 + col;
            #pragma unroll
            for (int r = 0; r < 4; ++r)
                op[(quad*4 + r)*1024 + p] = leaky(a3[j][r] + bv[r]);
        }
    }
}

extern "C" void kernel_launch(void* const* d_in, const int* in_sizes, int n_in,
                              void* d_out, int out_size, void* d_ws, size_t ws_size,
                              hipStream_t stream) {
    const float* feats = (const float*)d_in[0];
    const int*   edges = (const int*)  d_in[1];
    const float* w1 = (const float*)d_in[2];
    const float* b1 = (const float*)d_in[3];
    const float* w2 = (const float*)d_in[4];
    const float* b2 = (const float*)d_in[5];
    const float* w3 = (const float*)d_in[6];
    const float* b3 = (const float*)d_in[7];
    float* out = (float*)d_out;

    // ws layout: fcl 32 MiB | deg 4 KiB | adj 256 KiB  (~32.3 MiB total)
    _Float16* fcl = (_Float16*)d_ws;
    int* deg = (int*)((char*)d_ws + (32u << 20));
    int* adj = deg + NIMG;

    hipMemsetAsync(deg, 0, NIMG * sizeof(int), stream);
    build_adj<<<dim3(NEDGE/256), dim3(256), 0, stream>>>(edges, deg, adj);
    transpose_kernel<<<dim3(NIMG), dim3(256), 0, stream>>>(feats, fcl);
    conv_kernel<<<dim3(NIMG), dim3(1024), 0, stream>>>(fcl, deg, adj,
                                                       w1, b1, w2, b2, w3, b3, out);
}